// Round 4
// baseline (207.310 us; speedup 1.0000x reference)
//
#include <hip/hip_runtime.h>
#include <stdint.h>

typedef __bf16 bf16;
typedef __bf16 bf16x8 __attribute__((ext_vector_type(8)));
typedef float f32x4 __attribute__((ext_vector_type(4)));

#define AS1 __attribute__((address_space(1)))
#define AS3 __attribute__((address_space(3)))

__device__ __forceinline__ void gload_lds16(const void* g, void* l) {
    __builtin_amdgcn_global_load_lds((const AS1 uint32_t*)g, (AS3 uint32_t*)l, 16, 0, 0);
}

// ---------------------------------------------------------------------------
// NT GEMM: C[m,n] = sum_k A[m,k]*B[n,k] + bias[n], A,B row-major bf16.
// BK=64: 16 K-iterations (half the barrier/vmcnt(0) drains of BK=32).
// LDS 32 KB total. Output type templated (fp32 for final, bf16 for xp).
// Grid: (M/BM, N/BN) — blockIdx.x = A-row tile for XCD-local A reuse.
// ---------------------------------------------------------------------------
#define BM 128
#define BN 128
#define BK 64

template <typename OT>
__global__ __launch_bounds__(256, 2) void gemm_nt(
    const bf16* __restrict__ A, const bf16* __restrict__ B,
    const float* __restrict__ bias, OT* __restrict__ C,
    int M, int N, int K)
{
    __shared__ bf16 smA[BM * BK];   // 16 KB
    __shared__ bf16 smB[BN * BK];   // 16 KB

    const int tid  = threadIdx.x;
    const int wave = tid >> 6;
    const int lane = tid & 63;
    const int wm = (wave >> 1) * 64;
    const int wn = (wave & 1) * 64;
    const int rowA0 = blockIdx.x * BM;   // M tile (XCD-local reuse)
    const int rowB0 = blockIdx.y * BN;   // N tile

    f32x4 acc[4][4] = {};

    const int g  = lane >> 4;      // 0..3
    const int rm = lane & 15;

    for (int k0 = 0; k0 < K; k0 += BK) {
        // ---- stage A,B tiles: 4 issues x 256 lanes x 16B each ----
        #pragma unroll
        for (int i = 0; i < 4; ++i) {
            int slot = i * 256 + tid;          // 1024 slots of 16B per tile
            int row  = slot >> 3;              // 0..127
            int kgs  = slot & 7;               // slot k-group (8 per row)
            int kd   = kgs ^ ((row >> 1) & 7); // swizzled data k-group
            const bf16* ga = A + (size_t)(rowA0 + row) * K + k0 + kd * 8;
            const bf16* gb = B + (size_t)(rowB0 + row) * K + k0 + kd * 8;
            int ldsbase = (i * 256 + (wave << 6)) * 8;   // wave-uniform, elems
            gload_lds16(ga, &smA[ldsbase]);
            gload_lds16(gb, &smB[ldsbase]);
        }
        __syncthreads();

        // ---- two k=32 sub-steps ----
        #pragma unroll
        for (int s = 0; s < 2; ++s) {
            bf16x8 af[4], bfr[4];
            #pragma unroll
            for (int mi = 0; mi < 4; ++mi) {
                int row  = wm + mi * 16 + rm;
                int slot = row * 8 + ((s * 4 + g) ^ ((row >> 1) & 7));
                af[mi] = *(const bf16x8*)&smA[slot * 8];
            }
            #pragma unroll
            for (int ni = 0; ni < 4; ++ni) {
                int row  = wn + ni * 16 + rm;
                int slot = row * 8 + ((s * 4 + g) ^ ((row >> 1) & 7));
                bfr[ni] = *(const bf16x8*)&smB[slot * 8];
            }
            #pragma unroll
            for (int mi = 0; mi < 4; ++mi)
                #pragma unroll
                for (int ni = 0; ni < 4; ++ni)
                    acc[mi][ni] = __builtin_amdgcn_mfma_f32_16x16x32_bf16(
                        af[mi], bfr[ni], acc[mi][ni], 0, 0, 0);
        }
        __syncthreads();
    }

    // ---- epilogue: C/D layout col=lane&15, row=(lane>>4)*4+reg ----
    const int quad = lane >> 4;
    #pragma unroll
    for (int ni = 0; ni < 4; ++ni) {
        int col = rowB0 + wn + ni * 16 + rm;
        float bcol = bias[col];
        #pragma unroll
        for (int mi = 0; mi < 4; ++mi) {
            #pragma unroll
            for (int r = 0; r < 4; ++r) {
                int rowc = rowA0 + wm + mi * 16 + quad * 4 + r;
                C[(size_t)rowc * N + col] = (OT)(acc[mi][ni][r] + bcol);
            }
        }
    }
}

// ---------------------------------------------------------------------------
// fused fp32 -> bf16 cast of x, W_in, W_out (one launch)
// ---------------------------------------------------------------------------
__global__ void cast_all_kernel(const float* __restrict__ x, bf16* __restrict__ xb,
                                const float* __restrict__ wi, bf16* __restrict__ wib,
                                const float* __restrict__ wo, bf16* __restrict__ wob)
{
    const int NX8 = (2 * 4096 * 1024) / 8;
    const int NW8 = (1024 * 1024) / 8;
    int i = blockIdx.x * 256 + threadIdx.x;
    const float* in; bf16* out; int idx;
    if (i < NX8)            { in = x;  out = xb;  idx = i; }
    else if (i < NX8 + NW8) { in = wi; out = wib; idx = i - NX8; }
    else                    { in = wo; out = wob; idx = i - NX8 - NW8; }
    const float4* p = (const float4*)in;
    float4 a = p[2 * idx], b = p[2 * idx + 1];
    bf16x8 o;
    o[0] = (bf16)a.x; o[1] = (bf16)a.y; o[2] = (bf16)a.z; o[3] = (bf16)a.w;
    o[4] = (bf16)b.x; o[5] = (bf16)b.y; o[6] = (bf16)b.z; o[7] = (bf16)b.w;
    *(bf16x8*)(out + 8 * idx) = o;
}

// ---------------------------------------------------------------------------
// c_compute: c[row,h,r] = sum_d xpb[row, h*128+d] * Wc[h,d,r]   (bf16 xp)
// One wave per row; lane handles 16 consecutive elements (head = lane>>3).
// ---------------------------------------------------------------------------
__global__ __launch_bounds__(256) void c_compute(
    const bf16* __restrict__ xpb, const float* __restrict__ Wc,
    float* __restrict__ cbuf)
{
    const int wave = threadIdx.x >> 6, lane = threadIdx.x & 63;
    const int row  = blockIdx.x * 4 + wave;
    const int h    = lane >> 3;
    const int d0   = (lane & 7) * 16;

    const bf16* xr = xpb + (size_t)row * 1024 + lane * 16;
    bf16x8 v0 = *(const bf16x8*)xr;
    bf16x8 v1 = *(const bf16x8*)(xr + 8);
    float p0 = 0.f, p1 = 0.f, p2 = 0.f, p3 = 0.f;
    #pragma unroll
    for (int i = 0; i < 16; ++i) {
        float xv = (i < 8) ? (float)v0[i & 7] : (float)v1[i & 7];
        float4 wr = *(const float4*)(Wc + h * 512 + (d0 + i) * 4);
        p0 += xv * wr.x; p1 += xv * wr.y; p2 += xv * wr.z; p3 += xv * wr.w;
    }
    #pragma unroll
    for (int off = 1; off <= 4; off <<= 1) {
        p0 += __shfl_xor(p0, off);
        p1 += __shfl_xor(p1, off);
        p2 += __shfl_xor(p2, off);
        p3 += __shfl_xor(p3, off);
    }
    if ((lane & 7) == 0) {
        float4 o = {p0, p1, p2, p3};
        *(float4*)(cbuf + (size_t)row * 32 + h * 4) = o;
    }
}

// ---------------------------------------------------------------------------
// head_mix2: register sliding-window conv over bf16 xp.
// Grid (8, 512): linear id = h + 8*y -> head h pinned to XCD h (L2-local
// window re-reads). Thread owns (h,d) column and T=8 rows.
// ---------------------------------------------------------------------------
__constant__ int KS_c[8] = {3, 3, 7, 7, 11, 11, 21, 21};

template <int K>
__device__ __forceinline__ void mix_body(
    int h, int d, int n0, const bf16* __restrict__ xpb,
    const float* __restrict__ cbuf, const float* __restrict__ Aw,
    const float* __restrict__ Vw, const float* __restrict__ basew,
    float alpha, bf16* __restrict__ y)
{
    constexpr int T = 8;
    constexpr int W = T + K - 1;
    constexpr int pad = K / 2;
    const int nloc = n0 & 4095;

    float w[W];
    #pragma unroll
    for (int j = 0; j < W; ++j) {
        int nl = nloc + j - pad;
        bool valid = (nl >= 0) && (nl < 4096);
        w[j] = valid ? (float)xpb[(size_t)(n0 + j - pad) * 1024 + h * 128 + d] : 0.f;
    }

    float s0[T] = {}, s1[T] = {}, s2[T] = {}, s3[T] = {}, tv[T] = {};
    const float* Ah = Aw + h * 84;
    const float* bh = basew + h * 2688 + d;
    #pragma unroll
    for (int j = 0; j < K; ++j) {
        float a0 = Ah[j], a1 = Ah[21 + j], a2 = Ah[42 + j], a3 = Ah[63 + j];
        float bbj = bh[j * 128];
        #pragma unroll
        for (int t = 0; t < T; ++t) {
            float x = w[t + j];
            s0[t] += a0 * x; s1[t] += a1 * x;
            s2[t] += a2 * x; s3[t] += a3 * x;
            tv[t] += bbj * x;
        }
    }

    float v0 = Vw[h * 512 + d],       v1 = Vw[h * 512 + 128 + d];
    float v2 = Vw[h * 512 + 256 + d], v3 = Vw[h * 512 + 384 + d];
    #pragma unroll
    for (int t = 0; t < T; ++t) {
        float4 c4 = *(const float4*)(cbuf + (size_t)(n0 + t) * 32 + h * 4);
        float o = alpha * (c4.x * v0 * s0[t] + c4.y * v1 * s1[t] +
                           c4.z * v2 * s2[t] + c4.w * v3 * s3[t])
                + (1.f - alpha) * tv[t];
        y[(size_t)(n0 + t) * 1024 + h * 128 + d] = (bf16)o;
    }
}

__global__ __launch_bounds__(256) void head_mix2(
    const bf16* __restrict__ xpb, const float* __restrict__ cbuf,
    const float* __restrict__ Aw, const float* __restrict__ Vw,
    const float* __restrict__ basew, const float* __restrict__ alphas,
    bf16* __restrict__ y)
{
    const int h   = blockIdx.x;
    const int d   = threadIdx.x & 127;
    const int sub = threadIdx.x >> 7;
    const int n0  = (blockIdx.y * 2 + sub) * 8;
    const float alpha = 1.f / (1.f + __expf(-alphas[h]));

    switch (KS_c[h]) {
        case 3:  mix_body<3>(h, d, n0, xpb, cbuf, Aw, Vw, basew, alpha, y); break;
        case 7:  mix_body<7 >(h, d, n0, xpb, cbuf, Aw, Vw, basew, alpha, y); break;
        case 11: mix_body<11>(h, d, n0, xpb, cbuf, Aw, Vw, basew, alpha, y); break;
        default: mix_body<21>(h, d, n0, xpb, cbuf, Aw, Vw, basew, alpha, y); break;
    }
}

// ---------------------------------------------------------------------------
extern "C" void kernel_launch(void* const* d_in, const int* in_sizes, int n_in,
                              void* d_out, int out_size, void* d_ws, size_t ws_size,
                              hipStream_t stream)
{
    const float* x      = (const float*)d_in[0];
    const float* W_in   = (const float*)d_in[1];
    const float* b_in   = (const float*)d_in[2];
    const float* W_out  = (const float*)d_in[3];
    const float* b_out  = (const float*)d_in[4];
    const float* Wc     = (const float*)d_in[5];
    const float* Aw     = (const float*)d_in[6];
    const float* Vw     = (const float*)d_in[7];
    const float* basew  = (const float*)d_in[8];
    const float* alphas = (const float*)d_in[9];
    float* out = (float*)d_out;

    const size_t MB = 1u << 20;
    char* ws = (char*)d_ws;
    bf16*  xb   = (bf16*) (ws);             // 16 MB: x bf16
    bf16*  wib  = (bf16*) (ws + 16 * MB);   //  2 MB: W_in bf16
    bf16*  wob  = (bf16*) (ws + 18 * MB);   //  2 MB: W_out bf16
    bf16*  xpb  = (bf16*) (ws + 20 * MB);   // 16 MB: x_proj bf16
    bf16*  yb   = (bf16*) (ws + 36 * MB);   // 16 MB: head-concat y bf16
    float* cbuf = (float*)(ws + 52 * MB);   //  1 MB: c coefficients

    const int NTOT8 = (2 * 4096 * 1024 + 2 * 1024 * 1024) / 8;

    cast_all_kernel<<<NTOT8 / 256, 256, 0, stream>>>(x, xb, W_in, wib, W_out, wob);

    gemm_nt<bf16><<<dim3(8192 / BM, 1024 / BN), 256, 0, stream>>>(
        xb, wib, b_in, xpb, 8192, 1024, 1024);

    c_compute<<<8192 / 4, 256, 0, stream>>>(xpb, Wc, cbuf);

    head_mix2<<<dim3(8, 512), 256, 0, stream>>>(
        xpb, cbuf, Aw, Vw, basew, alphas, yb);

    gemm_nt<float><<<dim3(8192 / BM, 1024 / BN), 256, 0, stream>>>(
        yb, wob, b_out, out, 8192, 1024, 1024);
}

// Round 5
// 178.375 us; speedup vs baseline: 1.1622x; 1.1622x over previous
//
#include <hip/hip_runtime.h>
#include <stdint.h>

typedef __bf16 bf16;
typedef __bf16 bf16x8 __attribute__((ext_vector_type(8)));
typedef float f32x4 __attribute__((ext_vector_type(4)));

#define AS1 __attribute__((address_space(1)))
#define AS3 __attribute__((address_space(3)))

__device__ __forceinline__ void gload_lds16(const void* g, void* l) {
    __builtin_amdgcn_global_load_lds((const AS1 uint32_t*)g, (AS3 uint32_t*)l, 16, 0, 0);
}

// ---------------------------------------------------------------------------
// NT GEMM: C[m,n] = sum_k A[m,k]*B[n,k] + bias[n], A,B row-major bf16.
// BM=128, BN=64, BK=64 -> grid 64x16 = 1024 blocks = 4 blocks/CU.
// 4 waves in 2x2: wave tile 64x32 (acc[4][2] of 16x16 MFMA).
// blockIdx.x = A-row tile: the 16 blocks sharing an A tile land on one XCD.
// ---------------------------------------------------------------------------
#define BM 128
#define BN 64
#define BK 64

template <typename OT>
__global__ __launch_bounds__(256, 4) void gemm_nt(
    const bf16* __restrict__ A, const bf16* __restrict__ B,
    const float* __restrict__ bias, OT* __restrict__ C,
    int M, int N, int K)
{
    __shared__ bf16 smA[BM * BK];   // 16 KB
    __shared__ bf16 smB[BN * BK];   //  8 KB

    const int tid  = threadIdx.x;
    const int wave = tid >> 6;
    const int lane = tid & 63;
    const int wm = (wave >> 1) * 64;   // 0,64
    const int wn = (wave & 1) * 32;    // 0,32
    const int rowA0 = blockIdx.x * BM;
    const int rowB0 = blockIdx.y * BN;

    f32x4 acc[4][2] = {};

    const int g  = lane >> 4;      // 0..3
    const int rm = lane & 15;

    for (int k0 = 0; k0 < K; k0 += BK) {
        // ---- stage A: 1024 slots (4 passes), B: 512 slots (2 passes) ----
        #pragma unroll
        for (int i = 0; i < 4; ++i) {
            int slot = i * 256 + tid;
            int row  = slot >> 3;
            int kg   = slot & 7;
            int kd   = kg ^ ((row >> 1) & 7);
            gload_lds16(A + (size_t)(rowA0 + row) * K + k0 + kd * 8, &smA[slot * 8]);
        }
        #pragma unroll
        for (int i = 0; i < 2; ++i) {
            int slot = i * 256 + tid;
            int row  = slot >> 3;              // 0..63
            int kg   = slot & 7;
            int kd   = kg ^ ((row >> 1) & 7);
            gload_lds16(B + (size_t)(rowB0 + row) * K + k0 + kd * 8, &smB[slot * 8]);
        }
        __syncthreads();

        #pragma unroll
        for (int s = 0; s < 2; ++s) {
            bf16x8 af[4], bfr[2];
            #pragma unroll
            for (int mi = 0; mi < 4; ++mi) {
                int row  = wm + mi * 16 + rm;
                int slot = row * 8 + ((s * 4 + g) ^ ((row >> 1) & 7));
                af[mi] = *(const bf16x8*)&smA[slot * 8];
            }
            #pragma unroll
            for (int ni = 0; ni < 2; ++ni) {
                int row  = wn + ni * 16 + rm;
                int slot = row * 8 + ((s * 4 + g) ^ ((row >> 1) & 7));
                bfr[ni] = *(const bf16x8*)&smB[slot * 8];
            }
            #pragma unroll
            for (int mi = 0; mi < 4; ++mi)
                #pragma unroll
                for (int ni = 0; ni < 2; ++ni)
                    acc[mi][ni] = __builtin_amdgcn_mfma_f32_16x16x32_bf16(
                        af[mi], bfr[ni], acc[mi][ni], 0, 0, 0);
        }
        __syncthreads();
    }

    // ---- epilogue: C/D layout col=lane&15, row=(lane>>4)*4+reg ----
    const int quad = lane >> 4;
    #pragma unroll
    for (int ni = 0; ni < 2; ++ni) {
        int col = rowB0 + wn + ni * 16 + rm;
        float bcol = bias[col];
        #pragma unroll
        for (int mi = 0; mi < 4; ++mi) {
            #pragma unroll
            for (int r = 0; r < 4; ++r) {
                int rowc = rowA0 + wm + mi * 16 + quad * 4 + r;
                C[(size_t)rowc * N + col] = (OT)(acc[mi][ni][r] + bcol);
            }
        }
    }
}

// ---------------------------------------------------------------------------
// fused fp32 -> bf16 cast of x, W_in, W_out (one launch)
// ---------------------------------------------------------------------------
__global__ void cast_all_kernel(const float* __restrict__ x, bf16* __restrict__ xb,
                                const float* __restrict__ wi, bf16* __restrict__ wib,
                                const float* __restrict__ wo, bf16* __restrict__ wob)
{
    const int NX8 = (2 * 4096 * 1024) / 8;
    const int NW8 = (1024 * 1024) / 8;
    int i = blockIdx.x * 256 + threadIdx.x;
    const float* in; bf16* out; int idx;
    if (i < NX8)            { in = x;  out = xb;  idx = i; }
    else if (i < NX8 + NW8) { in = wi; out = wib; idx = i - NX8; }
    else                    { in = wo; out = wob; idx = i - NX8 - NW8; }
    const float4* p = (const float4*)in;
    float4 a = p[2 * idx], b = p[2 * idx + 1];
    bf16x8 o;
    o[0] = (bf16)a.x; o[1] = (bf16)a.y; o[2] = (bf16)a.z; o[3] = (bf16)a.w;
    o[4] = (bf16)b.x; o[5] = (bf16)b.y; o[6] = (bf16)b.z; o[7] = (bf16)b.w;
    *(bf16x8*)(out + 8 * idx) = o;
}

// ---------------------------------------------------------------------------
// c_compute: c[row,h,r] = sum_d xpb[row, h*128+d] * Wc[h,d,r]   (bf16 xp)
// ---------------------------------------------------------------------------
__global__ __launch_bounds__(256) void c_compute(
    const bf16* __restrict__ xpb, const float* __restrict__ Wc,
    float* __restrict__ cbuf)
{
    const int wave = threadIdx.x >> 6, lane = threadIdx.x & 63;
    const int row  = blockIdx.x * 4 + wave;
    const int h    = lane >> 3;
    const int d0   = (lane & 7) * 16;

    const bf16* xr = xpb + (size_t)row * 1024 + lane * 16;
    bf16x8 v0 = *(const bf16x8*)xr;
    bf16x8 v1 = *(const bf16x8*)(xr + 8);
    float p0 = 0.f, p1 = 0.f, p2 = 0.f, p3 = 0.f;
    #pragma unroll
    for (int i = 0; i < 16; ++i) {
        float xv = (i < 8) ? (float)v0[i & 7] : (float)v1[i & 7];
        float4 wr = *(const float4*)(Wc + h * 512 + (d0 + i) * 4);
        p0 += xv * wr.x; p1 += xv * wr.y; p2 += xv * wr.z; p3 += xv * wr.w;
    }
    #pragma unroll
    for (int off = 1; off <= 4; off <<= 1) {
        p0 += __shfl_xor(p0, off);
        p1 += __shfl_xor(p1, off);
        p2 += __shfl_xor(p2, off);
        p3 += __shfl_xor(p3, off);
    }
    if ((lane & 7) == 0) {
        float4 o = {p0, p1, p2, p3};
        *(float4*)(cbuf + (size_t)row * 32 + h * 4) = o;
    }
}

// ---------------------------------------------------------------------------
// head_mix3: LDS-staged sliding-window conv.
// Grid (512, 8): blockIdx.x = 16-row tile (stripes over XCDs -> balanced),
// blockIdx.y = head. Block stages rows [r0-pad, r0+16+pad) x 128 d into LDS
// (clamped; out-of-batch zeroed at read), then 256 threads = 128 d x 2 row
// halves compute T=8 rows each from LDS windows.
// ---------------------------------------------------------------------------
__constant__ int KS_c[8] = {3, 3, 7, 7, 11, 11, 21, 21};

template <int K>
__device__ __forceinline__ void mix_body3(
    int h, int tid, int r0, const bf16* __restrict__ xpb,
    const float* __restrict__ cbuf, const float* __restrict__ Aw,
    const float* __restrict__ Vw, const float* __restrict__ basew,
    float alpha, bf16* __restrict__ y, bf16* sx)
{
    constexpr int T   = 8;
    constexpr int pad = K / 2;
    constexpr int R   = 16 + 2 * pad;    // staged rows
    constexpr int S   = R * 16;          // 16B slots
    constexpr int NP  = (S + 255) / 256;

    #pragma unroll
    for (int p = 0; p < NP; ++p) {
        int slot = p * 256 + tid;
        if (slot < S) {
            int lrow = slot >> 4;
            int lc   = slot & 15;
            int grow = r0 - pad + lrow;
            grow = min(max(grow, 0), 8191);
            gload_lds16(xpb + (size_t)grow * 1024 + h * 128 + lc * 8,
                        sx + slot * 8);
        }
    }
    __syncthreads();

    const int d   = tid & 127;
    const int sub = tid >> 7;
    const int lr0 = sub * 8;
    const int nb  = (r0 & 4095) + sub * 8;   // batch-local first output row

    float w[T + K - 1];
    #pragma unroll
    for (int j = 0; j < T + K - 1; ++j) {
        int nl = nb + j - pad;
        float v = (float)sx[(lr0 + j) * 128 + d];
        w[j] = (nl >= 0 && nl < 4096) ? v : 0.f;
    }

    float s0[T] = {}, s1[T] = {}, s2[T] = {}, s3[T] = {}, tv[T] = {};
    const float* Ah = Aw + h * 84;
    const float* bh = basew + h * 2688 + d;
    #pragma unroll
    for (int j = 0; j < K; ++j) {
        float a0 = Ah[j], a1 = Ah[21 + j], a2 = Ah[42 + j], a3 = Ah[63 + j];
        float bbj = bh[j * 128];
        #pragma unroll
        for (int t = 0; t < T; ++t) {
            float x = w[t + j];
            s0[t] += a0 * x; s1[t] += a1 * x;
            s2[t] += a2 * x; s3[t] += a3 * x;
            tv[t] += bbj * x;
        }
    }

    float v0 = Vw[h * 512 + d],       v1 = Vw[h * 512 + 128 + d];
    float v2 = Vw[h * 512 + 256 + d], v3 = Vw[h * 512 + 384 + d];
    #pragma unroll
    for (int t = 0; t < T; ++t) {
        int rowo = r0 + sub * 8 + t;
        float4 c4 = *(const float4*)(cbuf + (size_t)rowo * 32 + h * 4);
        float o = alpha * (c4.x * v0 * s0[t] + c4.y * v1 * s1[t] +
                           c4.z * v2 * s2[t] + c4.w * v3 * s3[t])
                + (1.f - alpha) * tv[t];
        y[(size_t)rowo * 1024 + h * 128 + d] = (bf16)o;
    }
}

__global__ __launch_bounds__(256, 4) void head_mix3(
    const bf16* __restrict__ xpb, const float* __restrict__ cbuf,
    const float* __restrict__ Aw, const float* __restrict__ Vw,
    const float* __restrict__ basew, const float* __restrict__ alphas,
    bf16* __restrict__ y)
{
    __shared__ bf16 sx[36 * 128];   // max staged window (K=21): 9216 B
    const int h  = blockIdx.y;
    const int r0 = blockIdx.x * 16;
    const float alpha = 1.f / (1.f + __expf(-alphas[h]));

    switch (KS_c[h]) {
        case 3:  mix_body3<3 >(h, threadIdx.x, r0, xpb, cbuf, Aw, Vw, basew, alpha, y, sx); break;
        case 7:  mix_body3<7 >(h, threadIdx.x, r0, xpb, cbuf, Aw, Vw, basew, alpha, y, sx); break;
        case 11: mix_body3<11>(h, threadIdx.x, r0, xpb, cbuf, Aw, Vw, basew, alpha, y, sx); break;
        default: mix_body3<21>(h, threadIdx.x, r0, xpb, cbuf, Aw, Vw, basew, alpha, y, sx); break;
    }
}

// ---------------------------------------------------------------------------
extern "C" void kernel_launch(void* const* d_in, const int* in_sizes, int n_in,
                              void* d_out, int out_size, void* d_ws, size_t ws_size,
                              hipStream_t stream)
{
    const float* x      = (const float*)d_in[0];
    const float* W_in   = (const float*)d_in[1];
    const float* b_in   = (const float*)d_in[2];
    const float* W_out  = (const float*)d_in[3];
    const float* b_out  = (const float*)d_in[4];
    const float* Wc     = (const float*)d_in[5];
    const float* Aw     = (const float*)d_in[6];
    const float* Vw     = (const float*)d_in[7];
    const float* basew  = (const float*)d_in[8];
    const float* alphas = (const float*)d_in[9];
    float* out = (float*)d_out;

    const size_t MB = 1u << 20;
    char* ws = (char*)d_ws;
    bf16*  xb   = (bf16*) (ws);             // 16 MB: x bf16
    bf16*  wib  = (bf16*) (ws + 16 * MB);   //  2 MB: W_in bf16
    bf16*  wob  = (bf16*) (ws + 18 * MB);   //  2 MB: W_out bf16
    bf16*  xpb  = (bf16*) (ws + 20 * MB);   // 16 MB: x_proj bf16
    bf16*  yb   = (bf16*) (ws + 36 * MB);   // 16 MB: head-concat y bf16
    float* cbuf = (float*)(ws + 52 * MB);   //  1 MB: c coefficients

    const int NTOT8 = (2 * 4096 * 1024 + 2 * 1024 * 1024) / 8;

    cast_all_kernel<<<NTOT8 / 256, 256, 0, stream>>>(x, xb, W_in, wib, W_out, wob);

    gemm_nt<bf16><<<dim3(8192 / BM, 1024 / BN), 256, 0, stream>>>(
        xb, wib, b_in, xpb, 8192, 1024, 1024);

    c_compute<<<8192 / 4, 256, 0, stream>>>(xpb, Wc, cbuf);

    head_mix3<<<dim3(512, 8), 256, 0, stream>>>(
        xpb, cbuf, Aw, Vw, basew, alphas, yb);

    gemm_nt<float><<<dim3(8192 / BM, 1024 / BN), 256, 0, stream>>>(
        yb, wob, b_out, out, 8192, 1024, 1024);
}